// Round 10
// baseline (1311.518 us; speedup 1.0000x reference)
//
#include <hip/hip_runtime.h>

// Problem: B=16384, H=2048
//   bdnf = sigmoid(x @ W^T + b)
//   xs   = x * pm
//   fi   = xs * (xs @ M^T) * (0.5/H)
//   out  = xs + bdnf * fi
// Identity: xs @ M^T = x @ (M * pm[col])^T  -> both GEMMs share A = fp8(x).
//
// R10: single-buffered LDS (64 KB) -> 2 blocks/CU (16 waves). R9 found
// LDS_Block_Size=128KB forced 1 block/CU: all barrier/drain stalls were
// unhidden. Inter-block TLP now absorbs them (m114: cross-wave pipe overlap
// is automatic). Per tile: {stage 8 VMEM; vmcnt(0); bar; read A,W; lgkm0;
// MFMA acc1 SGB-interleaved with read M; lgkm0; MFMA acc2; bar}.
// __launch_bounds__(512,4) pins VGPR<=128 (R9 used exactly 128).
// MX fp8 dual GEMM: mfma_scale_f32_16x16x128_f8f6f4, scale_a=127 (1.0),
// scale_b=123 (2^-4, undoes x16 pre-scale that dodges e4m3 subnormals).

#define M_DIM 16384
#define H_DIM 2048
#define BM 256
#define BN 128
#define BKB 128            // K-tile = 128 fp8 elements = 128 B/row
#define NKT (H_DIM / BKB)  // 16 K-tiles
#define NTHREADS 512

typedef __attribute__((ext_vector_type(4))) int   intx4;
typedef __attribute__((ext_vector_type(8))) int   intx8;
typedef __attribute__((ext_vector_type(4))) float floatx4;

#define GPTR(p) ((const __attribute__((address_space(1))) void*)(p))
#define LPTR(p) ((__attribute__((address_space(3))) void*)(p))

__device__ __forceinline__ int pk4(float a, float b, float c, float d) {
    int v = __builtin_amdgcn_cvt_pk_fp8_f32(a, b, 0, false);
    v     = __builtin_amdgcn_cvt_pk_fp8_f32(c, d, v, true);
    return v;
}

// ---- pre-pass 1: x8 = fp8(x) ---------------------------------------------
__global__ void cvt_x8_kernel(const float* __restrict__ x,
                              unsigned char* __restrict__ x8, long n) {
    long stride = (long)gridDim.x * blockDim.x * 8;
    for (long j = ((long)blockIdx.x * blockDim.x + threadIdx.x) * 8; j < n; j += stride) {
        float4 v0 = *reinterpret_cast<const float4*>(x + j);
        float4 v1 = *reinterpret_cast<const float4*>(x + j + 4);
        int2 o;
        o.x = pk4(v0.x, v0.y, v0.z, v0.w);
        o.y = pk4(v1.x, v1.y, v1.z, v1.w);
        *reinterpret_cast<int2*>(x8 + j) = o;
    }
}

// ---- pre-pass 2: W8 = fp8(16*W); M8 = fp8(16*M*pm[col]) ------------------
__global__ void cvt_wm8_kernel(const float* __restrict__ W,
                               const float* __restrict__ Mk,
                               const float* __restrict__ pm,
                               unsigned char* __restrict__ W8,
                               unsigned char* __restrict__ M8, long n) {
    long stride = (long)gridDim.x * blockDim.x * 8;
    for (long j = ((long)blockIdx.x * blockDim.x + threadIdx.x) * 8; j < n; j += stride) {
        float4 w0 = *reinterpret_cast<const float4*>(W + j);
        float4 w1 = *reinterpret_cast<const float4*>(W + j + 4);
        float4 m0 = *reinterpret_cast<const float4*>(Mk + j);
        float4 m1 = *reinterpret_cast<const float4*>(Mk + j + 4);
        const long col = j & (H_DIM - 1);
        float4 p0 = *reinterpret_cast<const float4*>(pm + col);
        float4 p1 = *reinterpret_cast<const float4*>(pm + col + 4);
        int2 ow, om;
        ow.x = pk4(w0.x * 16.f, w0.y * 16.f, w0.z * 16.f, w0.w * 16.f);
        ow.y = pk4(w1.x * 16.f, w1.y * 16.f, w1.z * 16.f, w1.w * 16.f);
        om.x = pk4(m0.x * p0.x * 16.f, m0.y * p0.y * 16.f,
                   m0.z * p0.z * 16.f, m0.w * p0.w * 16.f);
        om.y = pk4(m1.x * p1.x * 16.f, m1.y * p1.y * 16.f,
                   m1.z * p1.z * 16.f, m1.w * p1.w * 16.f);
        *reinterpret_cast<int2*>(W8 + j) = ow;
        *reinterpret_cast<int2*>(M8 + j) = om;
    }
}

// swizzled fp8 frag read: 32 bytes (k-group g) of row `row`.
// LDS chunk slot c holds global chunk c^(row&7).
__device__ __forceinline__ intx8 frag8(const unsigned char* s, int row, int g) {
    const unsigned char* p = s + row * BKB;
    const int c0 = ((2 * g)     ^ (row & 7)) * 16;
    const int c1 = ((2 * g + 1) ^ (row & 7)) * 16;
    intx4 lo = *reinterpret_cast<const intx4*>(p + c0);
    intx4 hi = *reinterpret_cast<const intx4*>(p + c1);
    return (intx8){lo.x, lo.y, lo.z, lo.w, hi.x, hi.y, hi.z, hi.w};
}

#define GLDS(src, dst) __builtin_amdgcn_global_load_lds(GPTR(src), LPTR(dst), 16, 0, 0)

#define STAGE_A(kt) do { \
    GLDS(gA0 + (kt),                       &sA[(srow      ) * BKB + scol_l]); \
    GLDS(gA0 + (kt) + (size_t)64  * H_DIM, &sA[(srow +  64) * BKB + scol_l]); \
    GLDS(gA0 + (kt) + (size_t)128 * H_DIM, &sA[(srow + 128) * BKB + scol_l]); \
    GLDS(gA0 + (kt) + (size_t)192 * H_DIM, &sA[(srow + 192) * BKB + scol_l]); } while (0)

#define STAGE_W(kt) do { \
    GLDS(gW0 + (kt),                       &sW[(srow     ) * BKB + scol_l]); \
    GLDS(gW0 + (kt) + (size_t)64  * H_DIM, &sW[(srow + 64) * BKB + scol_l]); } while (0)

#define STAGE_M(kt) do { \
    GLDS(gM0 + (kt),                       &sM[(srow     ) * BKB + scol_l]); \
    GLDS(gM0 + (kt) + (size_t)64  * H_DIM, &sM[(srow + 64) * BKB + scol_l]); } while (0)

#define BAR()  __builtin_amdgcn_s_barrier()
#define SBAR() __builtin_amdgcn_sched_barrier(0)
#define LGK0() do { asm volatile("s_waitcnt lgkmcnt(0)" ::: "memory"); SBAR(); } while (0)
#define VMC(n) asm volatile("s_waitcnt vmcnt(" #n ")" ::: "memory")
#define SGB(mask, n) __builtin_amdgcn_sched_group_barrier(mask, n, 0)

// scale_a = 127 (2^0) for x; scale_b = 123 (2^-4) undoes the *16 pre-scale.
#define MFMASC(a, b, c) \
    __builtin_amdgcn_mfma_scale_f32_16x16x128_f8f6f4(a, b, c, 0, 0, 0, 127, 0, 123)

#define RD_A(dst) do { \
    _Pragma("unroll") for (int m_ = 0; m_ < 4; ++m_) \
        dst[m_] = frag8(sA, arow + m_ * 16, lg); } while (0)
#define RD_B(dst, sb) do { \
    _Pragma("unroll") for (int n_ = 0; n_ < 4; ++n_) \
        dst[n_] = frag8(sb, brw + n_ * 16, lg); } while (0)

#define MM(acc, av, bv) do { \
    _Pragma("unroll") for (int m_ = 0; m_ < 4; ++m_) \
    _Pragma("unroll") for (int n_ = 0; n_ < 4; ++n_) \
        acc[m_][n_] = MFMASC(av[m_], bv[n_], acc[m_][n_]); } while (0)

// ---- fused dual-GEMM + epilogue ------------------------------------------
__global__ __launch_bounds__(NTHREADS, 4)
void fused_gemm_kernel(const unsigned char* __restrict__ x8,
                       const unsigned char* __restrict__ W8,
                       const unsigned char* __restrict__ M8,
                       const float* __restrict__ x,
                       const float* __restrict__ bias,
                       const float* __restrict__ pm,
                       float* __restrict__ out) {
    __shared__ __align__(16) unsigned char sA[BM * BKB];  // 32 KB
    __shared__ __align__(16) unsigned char sW[BN * BKB];  // 16 KB
    __shared__ __align__(16) unsigned char sM[BN * BKB];  // 16 KB

    const int t    = threadIdx.x;
    const int brow = blockIdx.y * BM;
    const int bcol = blockIdx.x * BN;

    // staging: thread t covers row srow (+64/128/192), 16B chunk (t&7);
    // LDS dest linear, global source chunk pre-swizzled with srow&7.
    const int srow   = t >> 3;
    const int chunk  = t & 7;
    const int scol_l = chunk * 16;
    const int scol_g = (chunk ^ (srow & 7)) * 16;

    const int w    = t >> 6;
    const int lane = t & 63;
    const int wr   = w >> 1;             // 0..3 : 64-row strip
    const int wc   = w & 1;              // 0..1 : 64-col strip
    const int lrow = lane & 15;
    const int lg   = lane >> 4;          // k-group: holds k [32*lg, 32*lg+32)
    const int arow = wr * 64 + lrow;     // A-frag base row (+m*16)
    const int brw  = wc * 64 + lrow;     // B-frag base row (+n*16)

    floatx4 acc1[4][4], acc2[4][4];
#pragma unroll
    for (int m = 0; m < 4; ++m)
#pragma unroll
        for (int n = 0; n < 4; ++n) {
            acc1[m][n] = (floatx4){0.f, 0.f, 0.f, 0.f};
            acc2[m][n] = (floatx4){0.f, 0.f, 0.f, 0.f};
        }

    const unsigned char* gA0 = x8 + (size_t)(brow + srow) * H_DIM + scol_g;
    const unsigned char* gW0 = W8 + (size_t)(bcol + srow) * H_DIM + scol_g;
    const unsigned char* gM0 = M8 + (size_t)(bcol + srow) * H_DIM + scol_g;

    intx8 aF[4], bW[4], bM[4];

#pragma unroll 1
    for (int i = 0; i < NKT; ++i) {
        const int kt = i * BKB;
        // stage tile i into the (single) buffers
        STAGE_A(kt); STAGE_W(kt); STAGE_M(kt);
        VMC(0);                 // own stages landed
        BAR();                  // everyone's landed -> LDS tile valid
        RD_A(aF); RD_B(bW, sW);
        LGK0();
        __builtin_amdgcn_s_setprio(1);
        RD_B(bM, sM);
        MM(acc1, aF, bW);
        _Pragma("unroll") for (int i_ = 0; i_ < 8; ++i_) { SGB(0x8, 2); SGB(0x100, 1); }
        __builtin_amdgcn_s_setprio(0);
        LGK0();
        __builtin_amdgcn_s_setprio(1);
        MM(acc2, aF, bM);
        __builtin_amdgcn_s_setprio(0);
        SBAR();
        BAR();                  // all readers done; next stage may overwrite
    }

    // epilogue: out = xs + sigmoid(S1+b) * xs * S2 * (0.5/H), xs = x*pm (fp32)
    const float c = 0.5f / (float)H_DIM;
#pragma unroll
    for (int n = 0; n < 4; ++n) {
        const int gcol = bcol + wc * 64 + n * 16 + lrow;
        const float bj  = bias[gcol];
        const float pmj = pm[gcol];
#pragma unroll
        for (int m = 0; m < 4; ++m) {
            floatx4 a1 = acc1[m][n];
            floatx4 a2 = acc2[m][n];
            const int growb = brow + wr * 64 + m * 16 + (lane >> 4) * 4;
#pragma unroll
            for (int r = 0; r < 4; ++r) {
                const size_t idx = (size_t)(growb + r) * H_DIM + gcol;
                const float xs  = x[idx] * pmj;
                const float s1  = a1[r] + bj;
                const float sig = 1.0f / (1.0f + __expf(-s1));
                out[idx] = xs + sig * (xs * a2[r] * c);
            }
        }
    }
}

extern "C" void kernel_launch(void* const* d_in, const int* in_sizes, int n_in,
                              void* d_out, int out_size, void* d_ws, size_t ws_size,
                              hipStream_t stream) {
    const float* x   = (const float*)d_in[0];
    const float* W   = (const float*)d_in[1];
    const float* b   = (const float*)d_in[2];
    const float* pm  = (const float*)d_in[3];
    const float* Mk  = (const float*)d_in[4];
    float* out = (float*)d_out;

    const long n_x = (long)M_DIM * H_DIM;      // 33.5M
    const long n_w = (long)H_DIM * H_DIM;      // 4.2M

    // workspace layout (bytes): x8 | W8 | M8  -> ~42 MB total
    unsigned char* x8 = (unsigned char*)d_ws;
    unsigned char* W8 = x8 + n_x;
    unsigned char* M8 = W8 + n_w;

    cvt_x8_kernel<<<2048, 256, 0, stream>>>(x, x8, n_x);
    cvt_wm8_kernel<<<1024, 256, 0, stream>>>(W, Mk, pm, W8, M8, n_w);

    dim3 grid(H_DIM / BN, M_DIM / BM);   // (16, 64)
    fused_gemm_kernel<<<grid, NTHREADS, 0, stream>>>(x8, W8, M8, x, b, pm, out);
}

// Round 11
// 209.570 us; speedup vs baseline: 6.2581x; 6.2581x over previous
//
#include <hip/hip_runtime.h>

// Problem: B=16384, H=2048
//   bdnf = sigmoid(x @ W^T + b)
//   xs   = x * pm
//   fi   = xs * (xs @ M^T) * (0.5/H)
//   out  = xs + bdnf * fi
// Identity: xs @ M^T = x @ (M * pm[col])^T  -> both GEMMs share A = fp8(x).
//
// R11: two independent blocks per CU with FULL register budget.
// R10 failed because 512-thr blocks x 2 needed 128 regs/wave -> spill.
// Fix: 256-thr blocks (4 waves), BM=128 BN=64, dbuf LDS=64KB/block ->
// 2 blocks/CU (128KB LDS, 8 waves, 2/SIMD, 256 regs/wave). Two barrier
// domains: block A's lgkm0/vmcnt/barrier stalls hide under block B's MFMA.
// Tile body and vmcnt ledger identical to R8 (8 staged VMEM/thread/tile:
// A4,W2,M2; PH_W tail vmcnt(8) -> t's M landed; PH_M tail vmcnt(2) ->
// t+1's A,W landed). MX fp8 dual GEMM: mfma_scale_f32_16x16x128_f8f6f4,
// scale_a=127 (1.0), scale_b=123 (2^-4 undoes x16 pre-scale).

#define M_DIM 16384
#define H_DIM 2048
#define BM 128
#define BN 64
#define BKB 128            // K-tile = 128 fp8 elements = 128 B/row
#define NKT (H_DIM / BKB)  // 16 K-tiles
#define NTHREADS 256

typedef __attribute__((ext_vector_type(4))) int   intx4;
typedef __attribute__((ext_vector_type(8))) int   intx8;
typedef __attribute__((ext_vector_type(4))) float floatx4;

#define GPTR(p) ((const __attribute__((address_space(1))) void*)(p))
#define LPTR(p) ((__attribute__((address_space(3))) void*)(p))

__device__ __forceinline__ int pk4(float a, float b, float c, float d) {
    int v = __builtin_amdgcn_cvt_pk_fp8_f32(a, b, 0, false);
    v     = __builtin_amdgcn_cvt_pk_fp8_f32(c, d, v, true);
    return v;
}

// ---- pre-pass 1: x8 = fp8(x) ---------------------------------------------
__global__ void cvt_x8_kernel(const float* __restrict__ x,
                              unsigned char* __restrict__ x8, long n) {
    long stride = (long)gridDim.x * blockDim.x * 8;
    for (long j = ((long)blockIdx.x * blockDim.x + threadIdx.x) * 8; j < n; j += stride) {
        float4 v0 = *reinterpret_cast<const float4*>(x + j);
        float4 v1 = *reinterpret_cast<const float4*>(x + j + 4);
        int2 o;
        o.x = pk4(v0.x, v0.y, v0.z, v0.w);
        o.y = pk4(v1.x, v1.y, v1.z, v1.w);
        *reinterpret_cast<int2*>(x8 + j) = o;
    }
}

// ---- pre-pass 2: W8 = fp8(16*W); M8 = fp8(16*M*pm[col]) ------------------
__global__ void cvt_wm8_kernel(const float* __restrict__ W,
                               const float* __restrict__ Mk,
                               const float* __restrict__ pm,
                               unsigned char* __restrict__ W8,
                               unsigned char* __restrict__ M8, long n) {
    long stride = (long)gridDim.x * blockDim.x * 8;
    for (long j = ((long)blockIdx.x * blockDim.x + threadIdx.x) * 8; j < n; j += stride) {
        float4 w0 = *reinterpret_cast<const float4*>(W + j);
        float4 w1 = *reinterpret_cast<const float4*>(W + j + 4);
        float4 m0 = *reinterpret_cast<const float4*>(Mk + j);
        float4 m1 = *reinterpret_cast<const float4*>(Mk + j + 4);
        const long col = j & (H_DIM - 1);
        float4 p0 = *reinterpret_cast<const float4*>(pm + col);
        float4 p1 = *reinterpret_cast<const float4*>(pm + col + 4);
        int2 ow, om;
        ow.x = pk4(w0.x * 16.f, w0.y * 16.f, w0.z * 16.f, w0.w * 16.f);
        ow.y = pk4(w1.x * 16.f, w1.y * 16.f, w1.z * 16.f, w1.w * 16.f);
        om.x = pk4(m0.x * p0.x * 16.f, m0.y * p0.y * 16.f,
                   m0.z * p0.z * 16.f, m0.w * p0.w * 16.f);
        om.y = pk4(m1.x * p1.x * 16.f, m1.y * p1.y * 16.f,
                   m1.z * p1.z * 16.f, m1.w * p1.w * 16.f);
        *reinterpret_cast<int2*>(W8 + j) = ow;
        *reinterpret_cast<int2*>(M8 + j) = om;
    }
}

// swizzled fp8 frag read: 32 bytes (k-group g) of row `row`.
// LDS chunk slot c holds global chunk c^(row&7).
__device__ __forceinline__ intx8 frag8(const unsigned char* s, int row, int g) {
    const unsigned char* p = s + row * BKB;
    const int c0 = ((2 * g)     ^ (row & 7)) * 16;
    const int c1 = ((2 * g + 1) ^ (row & 7)) * 16;
    intx4 lo = *reinterpret_cast<const intx4*>(p + c0);
    intx4 hi = *reinterpret_cast<const intx4*>(p + c1);
    return (intx8){lo.x, lo.y, lo.z, lo.w, hi.x, hi.y, hi.z, hi.w};
}

#define GLDS(src, dst) __builtin_amdgcn_global_load_lds(GPTR(src), LPTR(dst), 16, 0, 0)

// 256 threads: srow = t>>3 in [0,32), chunk = t&7.
// A: 128 rows -> 4 passes (+0,+32,+64,+96); W/M: 64 rows -> 2 passes.
#define STAGE_A(b, kt) do { \
    GLDS(gA0 + (kt),                       &sA[b][(srow     ) * BKB + scol_l]); \
    GLDS(gA0 + (kt) + (size_t)32  * H_DIM, &sA[b][(srow + 32) * BKB + scol_l]); \
    GLDS(gA0 + (kt) + (size_t)64  * H_DIM, &sA[b][(srow + 64) * BKB + scol_l]); \
    GLDS(gA0 + (kt) + (size_t)96  * H_DIM, &sA[b][(srow + 96) * BKB + scol_l]); } while (0)

#define STAGE_W(b, kt) do { \
    GLDS(gW0 + (kt),                       &sW[b][(srow     ) * BKB + scol_l]); \
    GLDS(gW0 + (kt) + (size_t)32  * H_DIM, &sW[b][(srow + 32) * BKB + scol_l]); } while (0)

#define STAGE_M(b, kt) do { \
    GLDS(gM0 + (kt),                       &sM[b][(srow     ) * BKB + scol_l]); \
    GLDS(gM0 + (kt) + (size_t)32  * H_DIM, &sM[b][(srow + 32) * BKB + scol_l]); } while (0)

#define BAR()  __builtin_amdgcn_s_barrier()
#define SBAR() __builtin_amdgcn_sched_barrier(0)
#define LGK0() do { asm volatile("s_waitcnt lgkmcnt(0)" ::: "memory"); SBAR(); } while (0)
#define VMC(n) asm volatile("s_waitcnt vmcnt(" #n ")" ::: "memory")
#define SGB(mask, n) __builtin_amdgcn_sched_group_barrier(mask, n, 0)

// scale_a = 127 (2^0) for x; scale_b = 123 (2^-4) undoes the *16 pre-scale.
#define MFMASC(a, b, c) \
    __builtin_amdgcn_mfma_scale_f32_16x16x128_f8f6f4(a, b, c, 0, 0, 0, 127, 0, 123)

#define RD_A(dst, buf) do { \
    _Pragma("unroll") for (int m_ = 0; m_ < 4; ++m_) \
        dst[m_] = frag8(sA[buf], arow + m_ * 16, lg); } while (0)
#define RD_B(dst, sb, buf) do { \
    _Pragma("unroll") for (int n_ = 0; n_ < 2; ++n_) \
        dst[n_] = frag8(sb[buf], brw + n_ * 16, lg); } while (0)

#define MM(acc, av, bv) do { \
    _Pragma("unroll") for (int m_ = 0; m_ < 4; ++m_) \
    _Pragma("unroll") for (int n_ = 0; n_ < 2; ++n_) \
        acc[m_][n_] = MFMASC(av[m_], bv[n_], acc[m_][n_]); } while (0)

// PH_W(t): read A(t),W(t); stage A,W,M(t+1)->nt; acc1 += A*W; drain M(t)
#define PH_W(ct, nt, kst) do { \
    BAR(); \
    RD_A(aF, ct); RD_B(bW, sW, ct); \
    STAGE_A(nt, kst); STAGE_W(nt, kst); STAGE_M(nt, kst); \
    LGK0(); \
    __builtin_amdgcn_s_setprio(1); MM(acc1, aF, bW); __builtin_amdgcn_s_setprio(0); \
    VMC(8); } while (0)

// PH_M(t): read M(t); acc2 += A*M; drain A,W(t+1)
#define PH_M(ct) do { \
    BAR(); \
    RD_B(bM, sM, ct); \
    LGK0(); \
    __builtin_amdgcn_s_setprio(1); MM(acc2, aF, bM); __builtin_amdgcn_s_setprio(0); \
    VMC(2); } while (0)

// ---- fused dual-GEMM + epilogue ------------------------------------------
__global__ __launch_bounds__(NTHREADS, 2)
void fused_gemm_kernel(const unsigned char* __restrict__ x8,
                       const unsigned char* __restrict__ W8,
                       const unsigned char* __restrict__ M8,
                       const float* __restrict__ x,
                       const float* __restrict__ bias,
                       const float* __restrict__ pm,
                       float* __restrict__ out) {
    __shared__ __align__(16) unsigned char sA[2][BM * BKB];  // 2 x 16 KB
    __shared__ __align__(16) unsigned char sW[2][BN * BKB];  // 2 x 8 KB
    __shared__ __align__(16) unsigned char sM[2][BN * BKB];  // 2 x 8 KB
    // total 64 KB -> 2 blocks/CU

    const int t    = threadIdx.x;
    const int brow = blockIdx.y * BM;
    const int bcol = blockIdx.x * BN;

    // staging: thread t covers row srow (+32/64/96 for A, +32 for W/M),
    // 16B chunk (t&7); LDS dest linear, global source chunk pre-swizzled.
    const int srow   = t >> 3;
    const int chunk  = t & 7;
    const int scol_l = chunk * 16;
    const int scol_g = (chunk ^ (srow & 7)) * 16;

    const int w    = t >> 6;             // 4 waves
    const int lane = t & 63;
    const int wr   = w >> 1;             // 0..1 : 64-row strip
    const int wc   = w & 1;              // 0..1 : 32-col strip
    const int lrow = lane & 15;
    const int lg   = lane >> 4;          // k-group: holds k [32*lg, 32*lg+32)
    const int arow = wr * 64 + lrow;     // A-frag base row (+m*16, m<4)
    const int brw  = wc * 32 + lrow;     // B-frag base row (+n*16, n<2)

    floatx4 acc1[4][2], acc2[4][2];
#pragma unroll
    for (int m = 0; m < 4; ++m)
#pragma unroll
        for (int n = 0; n < 2; ++n) {
            acc1[m][n] = (floatx4){0.f, 0.f, 0.f, 0.f};
            acc2[m][n] = (floatx4){0.f, 0.f, 0.f, 0.f};
        }

    const unsigned char* gA0 = x8 + (size_t)(brow + srow) * H_DIM + scol_g;
    const unsigned char* gW0 = W8 + (size_t)(bcol + srow) * H_DIM + scol_g;
    const unsigned char* gM0 = M8 + (size_t)(bcol + srow) * H_DIM + scol_g;

    intx8 aF[4], bW[2], bM[2];

    // prologue: stage tile 0 (A4,W2,M2); drain A0,W0 (M0 drains at PH_W(0)'s
    // vmcnt(8)); first PH_W's BAR confirms all waves' stages.
    STAGE_A(0, 0); STAGE_W(0, 0); STAGE_M(0, 0);
    VMC(2);

#pragma unroll 1
    for (int i = 0; i < NKT / 2; ++i) {
        const int ka = ((2 * i + 1) * BKB) & (H_DIM - 1);  // stage for odd tile
        const int kb = ((2 * i + 2) * BKB) & (H_DIM - 1);  // stage for next even
        PH_W(0, 1, ka); PH_M(0);
        PH_W(1, 0, kb); PH_M(1);
    }

    // epilogue: out = xs + sigmoid(S1+b) * xs * S2 * (0.5/H), xs = x*pm (fp32)
    const float c = 0.5f / (float)H_DIM;
#pragma unroll
    for (int n = 0; n < 2; ++n) {
        const int gcol = bcol + wc * 32 + n * 16 + lrow;
        const float bj  = bias[gcol];
        const float pmj = pm[gcol];
#pragma unroll
        for (int m = 0; m < 4; ++m) {
            floatx4 a1 = acc1[m][n];
            floatx4 a2 = acc2[m][n];
            const int growb = brow + wr * 64 + m * 16 + (lane >> 4) * 4;
#pragma unroll
            for (int r = 0; r < 4; ++r) {
                const size_t idx = (size_t)(growb + r) * H_DIM + gcol;
                const float xs  = x[idx] * pmj;
                const float s1  = a1[r] + bj;
                const float sig = 1.0f / (1.0f + __expf(-s1));
                out[idx] = xs + sig * (xs * a2[r] * c);
            }
        }
    }
}

extern "C" void kernel_launch(void* const* d_in, const int* in_sizes, int n_in,
                              void* d_out, int out_size, void* d_ws, size_t ws_size,
                              hipStream_t stream) {
    const float* x   = (const float*)d_in[0];
    const float* W   = (const float*)d_in[1];
    const float* b   = (const float*)d_in[2];
    const float* pm  = (const float*)d_in[3];
    const float* Mk  = (const float*)d_in[4];
    float* out = (float*)d_out;

    const long n_x = (long)M_DIM * H_DIM;      // 33.5M
    const long n_w = (long)H_DIM * H_DIM;      // 4.2M

    // workspace layout (bytes): x8 | W8 | M8  -> ~42 MB total
    unsigned char* x8 = (unsigned char*)d_ws;
    unsigned char* W8 = x8 + n_x;
    unsigned char* M8 = W8 + n_w;

    cvt_x8_kernel<<<2048, 256, 0, stream>>>(x, x8, n_x);
    cvt_wm8_kernel<<<1024, 256, 0, stream>>>(W, Mk, pm, W8, M8, n_w);

    dim3 grid(H_DIM / BN, M_DIM / BM);   // (32, 128) = 4096 blocks
    fused_gemm_kernel<<<grid, NTHREADS, 0, stream>>>(x8, W8, M8, x, b, pm, out);
}